// Round 4
// baseline (392.566 us; speedup 1.0000x reference)
//
#include <hip/hip_runtime.h>

#define NB 16
#define CDIM 512
#define NHEAD 8
#define DHEAD 64
#define NSEQ 4096
#define O3 1536

typedef __attribute__((ext_vector_type(8))) short short8;
typedef __attribute__((ext_vector_type(4))) float f32x4;
typedef __attribute__((ext_vector_type(4))) unsigned u32x4;
typedef __attribute__((ext_vector_type(2))) unsigned u32x2;
typedef __attribute__((ext_vector_type(4))) float fvec4;

__device__ __forceinline__ float bf2f(unsigned short u){
  union { unsigned u; float f; } v; v.u = ((unsigned)u) << 16; return v.f;
}
__device__ __forceinline__ unsigned short f2bf(float f){
  union { float f; unsigned u; } v; v.f = f;
  unsigned r = v.u + 0x7fffu + ((v.u >> 16) & 1u);
  return (unsigned short)(r >> 16);
}
__device__ __forceinline__ unsigned pack2(float a, float b){
  return (unsigned)f2bf(a) | ((unsigned)f2bf(b) << 16);
}
__device__ __forceinline__ void gld_lds16(const void* g, void* l){
  __builtin_amdgcn_global_load_lds(
      (const __attribute__((address_space(1))) unsigned*)g,
      (__attribute__((address_space(3))) unsigned*)l, 16, 0, 0);
}

// ---- w_qkv f32 -> bf16 ----
__global__ __launch_bounds__(256) void k_conv_w(const float* __restrict__ w,
                                                unsigned short* __restrict__ o){
  int i = (blockIdx.x*256 + threadIdx.x)*4;
  fvec4 v = *(const fvec4*)(w + i);
  u32x2 p; p[0] = pack2(v[0], v[1]); p[1] = pack2(v[2], v[3]);
  *(u32x2*)(o + i) = p;
}

// ---- x [b][c][n] f32 -> xT [b][n][c] bf16 ----
__global__ __launch_bounds__(256) void k_transpose_x(const float* __restrict__ x,
                                                     unsigned short* __restrict__ xT){
  __shared__ unsigned short tile[64][65];
  int b = blockIdx.z, c0 = blockIdx.y*64, n0 = blockIdx.x*64;
  int t = threadIdx.x;
  const float* xb = x + ((size_t)b*CDIM + c0)*NSEQ + n0;
  #pragma unroll
  for (int i=0;i<4;i++){
    int idx = t + i*256;
    int r = idx>>4, c4 = (idx&15)*4;
    fvec4 v = *(const fvec4*)(xb + (size_t)r*NSEQ + c4);
    tile[r][c4]   = f2bf(v[0]);
    tile[r][c4+1] = f2bf(v[1]);
    tile[r][c4+2] = f2bf(v[2]);
    tile[r][c4+3] = f2bf(v[3]);
  }
  __syncthreads();
  unsigned short* ob = xT + ((size_t)b*NSEQ + n0)*CDIM + c0;
  #pragma unroll
  for (int i=0;i<4;i++){
    int idx = t + i*256;
    int r = idx>>4, c4 = (idx&15)*4;
    u32x2 p;
    p[0] = (unsigned)tile[c4][r]   | ((unsigned)tile[c4+1][r] << 16);
    p[1] = (unsigned)tile[c4+2][r] | ((unsigned)tile[c4+3][r] << 16);
    *(u32x2*)(ob + (size_t)r*CDIM + c4) = p;
  }
}

// ---- k/v GEMM, 8-phase 256x256 BK=64 schedule (T2+T3+T4+T5) ----
// 8 waves (2M x 4N), per-wave out 128x64, LDS 128 KiB double-buffered.
// Swizzle: off ^= ((off>>9)&3)<<5 on ds_read; inverse-permuted global src
// for global_load_lds (linear LDS dest). Counted vmcnt(2) per K-tile
// boundary; vmcnt(0) only at the last K-tile.
__global__ __launch_bounds__(512,2) void k_gemm_kv8(const unsigned short* __restrict__ A,
                                                    const unsigned short* __restrict__ Bt,
                                                    unsigned short* __restrict__ KV){
  __shared__ char lds[131072];
  int t = threadIdx.x, w = t>>6, l = t&63;
  int lr = l&15, kq = (l>>4)*8;
  int wm = w>>2, wn = w&3;
  int n0 = blockIdx.x*256, o0 = blockIdx.y*256, b = blockIdx.z;
  const unsigned short* Ab = A + (size_t)o0*CDIM;
  const unsigned short* Bb = Bt + ((size_t)b*NSEQ + n0)*CDIM;

  // stage unit h (16 KB): jh=h>>2 K-tile, part=h&3 (0=A-lo,1=A-hi,2=B-lo,3=B-hi)
  auto STAGE = [&](int h){
    if (h >= 32) return;
    int jh = h>>2, part = h&3;
    char* region = lds + (((jh&1)<<16) | ((part>>1)<<15));
    const unsigned short* g = (part < 2 ? Ab : Bb) + jh*64;
    int halfbase = (part&1)<<14;
    #pragma unroll
    for (int c=0;c<2;++c){
      int rel = halfbase + c*8192 + t*16;
      int srel = rel ^ (((rel>>9)&3)<<5);       // inverse swizzle on source
      gld_lds16(g + (size_t)(srel>>7)*CDIM + ((srel&127)>>1), region + rel);
    }
  };
  auto FRAG = [&](const char* region, int row, int kb)->short8{
    int off = row*128 + kb;
    off ^= ((off>>9)&3)<<5;                     // swizzled read
    return *(const short8*)(region + off);
  };

  f32x4 acc[8][4];
  #pragma unroll
  for (int mi=0;mi<8;mi++)
    #pragma unroll
    for (int ni=0;ni<4;ni++) acc[mi][ni] = (f32x4){0.f,0.f,0.f,0.f};

  #pragma unroll
  for (int h=0;h<5;++h) STAGE(h);               // prologue: K0 full + A-lo(K1)

  for (int j=0;j<8;++j){
    // ---- K-tile boundary: counted vmcnt, then barrier ----
    if (j==7){ asm volatile("s_waitcnt vmcnt(0)" ::: "memory"); }
    else     { asm volatile("s_waitcnt vmcnt(2)" ::: "memory"); }
    __builtin_amdgcn_sched_barrier(0);
    __builtin_amdgcn_s_barrier();
    const char* Ar = lds + ((j&1)<<16);
    const char* Br = Ar + 32768;
    short8 aF[4][2], bF0[2][2], bF1[2][2];
    // ---- phase 0: read A-mh0 + B-nh0, stage, MFMA quad (0,0) ----
    #pragma unroll
    for (int mi=0;mi<4;++mi)
      #pragma unroll
      for (int kk=0;kk<2;++kk)
        aF[mi][kk] = FRAG(Ar, wm*128 + mi*16 + lr, kk*64 + kq*2);
    #pragma unroll
    for (int ni=0;ni<2;++ni)
      #pragma unroll
      for (int kk=0;kk<2;++kk)
        bF0[ni][kk] = FRAG(Br, wn*64 + ni*16 + lr, kk*64 + kq*2);
    STAGE(4*j+5);
    __builtin_amdgcn_s_barrier();
    __builtin_amdgcn_s_setprio(1);
    #pragma unroll
    for (int mi=0;mi<4;++mi)
      #pragma unroll
      for (int ni=0;ni<2;++ni)
        #pragma unroll
        for (int kk=0;kk<2;++kk)
          acc[mi][ni] = __builtin_amdgcn_mfma_f32_16x16x32_bf16(aF[mi][kk], bF0[ni][kk], acc[mi][ni], 0, 0, 0);
    __builtin_amdgcn_s_setprio(0);
    __builtin_amdgcn_s_barrier();
    // ---- phase 1: read B-nh1, stage, MFMA quad (0,1) ----
    #pragma unroll
    for (int ni=0;ni<2;++ni)
      #pragma unroll
      for (int kk=0;kk<2;++kk)
        bF1[ni][kk] = FRAG(Br, wn*64 + 32 + ni*16 + lr, kk*64 + kq*2);
    STAGE(4*j+6);
    __builtin_amdgcn_s_barrier();
    __builtin_amdgcn_s_setprio(1);
    #pragma unroll
    for (int mi=0;mi<4;++mi)
      #pragma unroll
      for (int ni=0;ni<2;++ni)
        #pragma unroll
        for (int kk=0;kk<2;++kk)
          acc[mi][2+ni] = __builtin_amdgcn_mfma_f32_16x16x32_bf16(aF[mi][kk], bF1[ni][kk], acc[mi][2+ni], 0, 0, 0);
    __builtin_amdgcn_s_setprio(0);
    __builtin_amdgcn_s_barrier();
    // ---- phase 2: read A-mh1, stage, MFMA quad (1,1) ----
    #pragma unroll
    for (int mi=0;mi<4;++mi)
      #pragma unroll
      for (int kk=0;kk<2;++kk)
        aF[mi][kk] = FRAG(Ar, wm*128 + 64 + mi*16 + lr, kk*64 + kq*2);
    STAGE(4*j+7);
    __builtin_amdgcn_s_barrier();
    __builtin_amdgcn_s_setprio(1);
    #pragma unroll
    for (int mi=0;mi<4;++mi)
      #pragma unroll
      for (int ni=0;ni<2;++ni)
        #pragma unroll
        for (int kk=0;kk<2;++kk)
          acc[4+mi][2+ni] = __builtin_amdgcn_mfma_f32_16x16x32_bf16(aF[mi][kk], bF1[ni][kk], acc[4+mi][2+ni], 0, 0, 0);
    __builtin_amdgcn_s_setprio(0);
    __builtin_amdgcn_s_barrier();
    // ---- phase 3: stage A-lo(j+2) (guard: pin phase-2 reads before it), MFMA quad (1,0) ----
    __builtin_amdgcn_sched_barrier(0);
    STAGE(4*j+8);
    __builtin_amdgcn_s_barrier();
    __builtin_amdgcn_s_setprio(1);
    #pragma unroll
    for (int mi=0;mi<4;++mi)
      #pragma unroll
      for (int ni=0;ni<2;++ni)
        #pragma unroll
        for (int kk=0;kk<2;++kk)
          acc[4+mi][ni] = __builtin_amdgcn_mfma_f32_16x16x32_bf16(aF[mi][kk], bF0[ni][kk], acc[4+mi][ni], 0, 0, 0);
    __builtin_amdgcn_s_setprio(0);
    // (group-end barrier is the next boundary's vmcnt+barrier)
  }
  unsigned short* Cb = KV + (size_t)b*1024*NSEQ;
  #pragma unroll
  for (int mi=0;mi<8;++mi)
    #pragma unroll
    for (int ni=0;ni<4;++ni)
      #pragma unroll
      for (int r=0;r<4;++r){
        int row = o0 + wm*128 + mi*16 + (l>>4)*4 + r;
        int col = n0 + wn*64 + ni*16 + lr;
        Cb[(size_t)row*NSEQ + col] = f2bf(acc[mi][ni][r]);
      }
}

// ---- q GEMM + in-register head-softmax -> qsmT[b][n][c] bf16 ----
#define TS 136
__global__ __launch_bounds__(256) void k_gemm_q(const unsigned short* __restrict__ A,
                                                const unsigned short* __restrict__ Bt,
                                                unsigned short* __restrict__ qsmT){
  __shared__ unsigned short smem[64*TS];   // 17.4 KB; As/Bs alias first 16 KB
  unsigned short* As = smem;
  unsigned short* Bs = smem + 4096;
  int b = blockIdx.z;
  int n0 = blockIdx.x*128, o0 = blockIdx.y*128;
  const unsigned short* Bb = Bt + (size_t)b*NSEQ*CDIM;
  int t = threadIdx.x, w = t>>6, l = t&63;
  int lr = l&15, kq = (l>>4)*8;
  int wr = (w>>1)*64, wc = (w&1)*64;
  f32x4 acc[4][4];
  #pragma unroll
  for (int mi=0;mi<4;mi++)
    #pragma unroll
    for (int ni=0;ni<4;ni++) acc[mi][ni] = (f32x4){0.f,0.f,0.f,0.f};
  for (int k0=0;k0<CDIM;k0+=32){
    #pragma unroll
    for (int it=0;it<2;++it){
      int chunk = it*256 + t;
      int row = chunk>>2, kc = (chunk&3)*8;
      gld_lds16(A  + (size_t)(o0+row)*CDIM + k0 + kc, (char*)As + (size_t)chunk*16);
      gld_lds16(Bb + (size_t)(n0+row)*CDIM + k0 + kc, (char*)Bs + (size_t)chunk*16);
    }
    __syncthreads();
    short8 af[4], bfv[4];
    #pragma unroll
    for (int mi=0;mi<4;mi++) af[mi]  = *(const short8*)&As[(wr + mi*16 + lr)*32 + kq];
    #pragma unroll
    for (int ni=0;ni<4;ni++) bfv[ni] = *(const short8*)&Bs[(wc + ni*16 + lr)*32 + kq];
    #pragma unroll
    for (int mi=0;mi<4;mi++)
      #pragma unroll
      for (int ni=0;ni<4;ni++)
        acc[mi][ni] = __builtin_amdgcn_mfma_f32_16x16x32_bf16(af[mi], bfv[ni], acc[mi][ni], 0, 0, 0);
    __syncthreads();
  }
  // in-register softmax over d (wave's 64 rows = one head) per column
  unsigned pk[4][4][2];
  #pragma unroll
  for (int ni=0;ni<4;ni++){
    float mx = -1e30f;
    #pragma unroll
    for (int mi=0;mi<4;mi++)
      #pragma unroll
      for (int r=0;r<4;r++) mx = fmaxf(mx, acc[mi][ni][r]);
    mx = fmaxf(mx, __shfl_xor(mx, 16, 64));
    mx = fmaxf(mx, __shfl_xor(mx, 32, 64));
    float s = 0.f;
    #pragma unroll
    for (int mi=0;mi<4;mi++)
      #pragma unroll
      for (int r=0;r<4;r++){
        float p = __expf(acc[mi][ni][r] - mx);
        acc[mi][ni][r] = p; s += p;
      }
    s += __shfl_xor(s, 16, 64);
    s += __shfl_xor(s, 32, 64);
    float inv = 0.125f / s;
    #pragma unroll
    for (int mi=0;mi<4;mi++){
      pk[mi][ni][0] = pack2(acc[mi][ni][0]*inv, acc[mi][ni][1]*inv);
      pk[mi][ni][1] = pack2(acc[mi][ni][2]*inv, acc[mi][ni][3]*inv);
    }
  }
  #pragma unroll
  for (int ck=0;ck<2;++ck){
    if ((w&1) == ck){
      #pragma unroll
      for (int mi=0;mi<4;mi++)
        #pragma unroll
        for (int ni=0;ni<4;ni++){
          int idx = (ni*16 + lr)*TS + wr + mi*16 + (l>>4)*4;
          u32x2 p; p[0] = pk[mi][ni][0]; p[1] = pk[mi][ni][1];
          *(u32x2*)&smem[idx] = p;
        }
    }
    __syncthreads();
    int col = t>>2, rs = (t&3)*32;
    unsigned short* dst = qsmT + ((size_t)b*NSEQ + n0 + ck*64 + col)*CDIM + o0 + rs;
    #pragma unroll
    for (int j=0;j<4;++j)
      *(u32x4*)(dst + j*8) = *(const u32x4*)&smem[col*TS + rs + j*8];
    __syncthreads();
  }
}

// ---- k row stats over n, per (b, channel); KV rows 0..511 are k ----
__global__ __launch_bounds__(256) void k_kstats(const unsigned short* __restrict__ KV,
                                                float* __restrict__ kmax, float* __restrict__ ksum){
  int w = threadIdx.x>>6, l = threadIdx.x&63;
  int idx = blockIdx.x*4 + w;
  int b = idx>>9, row = idx&511;
  const unsigned short* kp = KV + ((size_t)b*1024 + row)*NSEQ;
  u32x4 kv[8];
  #pragma unroll
  for (int it=0;it<8;++it) kv[it] = ((const u32x4*)kp)[it*64 + l];
  float mx = -1e30f;
  #pragma unroll
  for (int it=0;it<8;++it)
    #pragma unroll
    for (int c=0;c<4;++c){
      unsigned u = kv[it][c];
      mx = fmaxf(mx, fmaxf(bf2f((unsigned short)u), bf2f((unsigned short)(u>>16))));
    }
  #pragma unroll
  for (int s=1;s<64;s<<=1) mx = fmaxf(mx, __shfl_xor(mx, s, 64));
  float sm = 0.f;
  #pragma unroll
  for (int it=0;it<8;++it)
    #pragma unroll
    for (int c=0;c<4;++c){
      unsigned u = kv[it][c];
      sm += __expf(bf2f((unsigned short)u) - mx) + __expf(bf2f((unsigned short)(u>>16)) - mx);
    }
  #pragma unroll
  for (int s=1;s<64;s<<=1) sm += __shfl_xor(sm, s, 64);
  if (l == 0){ kmax[idx] = mx; ksum[idx] = sm; }
}

// ---- partial context over n-chunk ----
__global__ __launch_bounds__(256) void k_context(const unsigned short* __restrict__ KV,
                                                 const float* __restrict__ kmax,
                                                 const float* __restrict__ ksum,
                                                 float* __restrict__ ctx4){
  __shared__ unsigned short Vs[64*64];
  int m = blockIdx.x, b = blockIdx.y, ch = blockIdx.z;
  int t = threadIdx.x, w = t>>6, l = t&63;
  int lr = l&15, kq = (l>>4)*8;
  const unsigned short* kbase = KV + ((size_t)b*1024 + m*64)*NSEQ;
  const unsigned short* vbase = KV + ((size_t)b*1024 + 512 + m*64)*NSEQ;
  int irow = w*16 + lr;
  float rmax = kmax[b*512 + m*64 + irow];
  f32x4 acc[4];
  #pragma unroll
  for (int jf=0;jf<4;++jf) acc[jf] = (f32x4){0.f,0.f,0.f,0.f};
  int nbeg = ch*1024, nend = nbeg + 1024;
  for (int n0=nbeg;n0<nend;n0+=64){
    #pragma unroll
    for (int it=0;it<2;++it){
      int chunk = it*256 + t;
      int row = chunk>>3, kc = (chunk&7)*8;
      gld_lds16(vbase + (size_t)row*NSEQ + n0 + kc, (char*)Vs + (size_t)chunk*16);
    }
    __syncthreads();
    #pragma unroll
    for (int kk=0;kk<2;++kk){
      u32x4 kraw = *(const u32x4*)(kbase + (size_t)irow*NSEQ + n0 + kk*32 + kq);
      short8 af;
      #pragma unroll
      for (int c=0;c<4;++c){
        unsigned u = kraw[c];
        float f0 = __expf(bf2f((unsigned short)u) - rmax);
        float f1 = __expf(bf2f((unsigned short)(u>>16)) - rmax);
        af[c*2]   = (short)f2bf(f0);
        af[c*2+1] = (short)f2bf(f1);
      }
      #pragma unroll
      for (int jf=0;jf<4;++jf){
        short8 bv = *(const short8*)&Vs[(jf*16+lr)*64 + kk*32 + kq];
        acc[jf] = __builtin_amdgcn_mfma_f32_16x16x32_bf16(af, bv, acc[jf], 0, 0, 0);
      }
    }
    __syncthreads();
  }
  float* cb = ctx4 + (((size_t)ch*NB + b)*NHEAD + m)*4096;
  #pragma unroll
  for (int jf=0;jf<4;++jf)
    #pragma unroll
    for (int r=0;r<4;++r){
      int i = w*16 + (l>>4)*4 + r;
      int j = jf*16 + lr;
      cb[i*64 + j] = acc[jf][r] / ksum[b*512 + m*64 + i];
    }
}

// ---- W_eff: z-split over o for parallelism ----
__global__ __launch_bounds__(256) void k_weff(const float* __restrict__ ctx4,
                                              const float* __restrict__ wout,
                                              unsigned short* __restrict__ weff){
  __shared__ float cs[64][65];
  int m = blockIdx.x, b = blockIdx.y, z = blockIdx.z;
  int t = threadIdx.x, w = t>>6, l = t&63;
  const float* cb = ctx4 + ((size_t)b*NHEAD + m)*4096;
  const size_t chs = (size_t)NB*NHEAD*4096;
  for (int idx=t; idx<4096; idx+=256)
    cs[idx>>6][idx&63] = cb[idx] + cb[idx+chs] + cb[idx+2*chs] + cb[idx+3*chs];
  __syncthreads();
  for (int oo=0;oo<32;++oo){
    int o = z*128 + w*32 + oo;
    float acc = 0.f;
    #pragma unroll
    for (int j=0;j<64;++j) acc += wout[(size_t)o*CDIM + m*64 + j] * cs[l][j];
    weff[((size_t)b*CDIM + o)*CDIM + m*64 + l] = f2bf(acc);
  }
}

// ---- fused final GEMM + bias + channel-LN: 512(o) x 128(n) per block ----
__global__ __launch_bounds__(512) void k_out_ln(const unsigned short* __restrict__ Weff,
                                                const unsigned short* __restrict__ QT,
                                                const float* __restrict__ bias,
                                                const float* __restrict__ g,
                                                float* __restrict__ out){
  __shared__ unsigned short As[512*32];   // 32 KB
  __shared__ unsigned short Bs[128*32];   //  8 KB
  __shared__ float lnS[128], lnS2[128];
  int b = blockIdx.y, n0 = blockIdx.x*128;
  const unsigned short* Ab = Weff + (size_t)b*CDIM*CDIM;
  const unsigned short* Bb = QT + ((size_t)b*NSEQ + n0)*CDIM;
  int t = threadIdx.x, w = t>>6, l = t&63;
  int lr = l&15, kq = (l>>4)*8;
  f32x4 acc[4][8];
  #pragma unroll
  for (int mi=0;mi<4;mi++)
    #pragma unroll
    for (int ni=0;ni<8;ni++) acc[mi][ni] = (f32x4){0.f,0.f,0.f,0.f};
  for (int k0=0;k0<CDIM;k0+=32){
    #pragma unroll
    for (int it=0;it<4;++it){
      int chunk = it*512 + t;
      int row = chunk>>2, kc = (chunk&3)*8;
      gld_lds16(Ab + (size_t)row*CDIM + k0 + kc, (char*)As + (size_t)chunk*16);
    }
    {
      int row = t>>2, kc = (t&3)*8;
      gld_lds16(Bb + (size_t)row*CDIM + k0 + kc, (char*)Bs + (size_t)t*16);
    }
    __syncthreads();
    short8 af[4], bfv[8];
    #pragma unroll
    for (int mi=0;mi<4;mi++) af[mi]  = *(const short8*)&As[(w*64 + mi*16 + lr)*32 + kq];
    #pragma unroll
    for (int ni=0;ni<8;ni++) bfv[ni] = *(const short8*)&Bs[(ni*16 + lr)*32 + kq];
    #pragma unroll
    for (int mi=0;mi<4;mi++)
      #pragma unroll
      for (int ni=0;ni<8;ni++)
        acc[mi][ni] = __builtin_amdgcn_mfma_f32_16x16x32_bf16(af[mi], bfv[ni], acc[mi][ni], 0, 0, 0);
    __syncthreads();
  }
  if (t < 128){ lnS[t] = 0.f; lnS2[t] = 0.f; }
  __syncthreads();
  float ps[8], ps2[8];
  #pragma unroll
  for (int ni=0;ni<8;ni++){ ps[ni]=0.f; ps2[ni]=0.f; }
  #pragma unroll
  for (int mi=0;mi<4;mi++)
    #pragma unroll
    for (int r=0;r<4;r++){
      int row = w*64 + mi*16 + (l>>4)*4 + r;
      float bb = bias[row];
      #pragma unroll
      for (int ni=0;ni<8;ni++){
        float v = acc[mi][ni][r] + bb;
        acc[mi][ni][r] = v;
        ps[ni] += v; ps2[ni] += v*v;
      }
    }
  #pragma unroll
  for (int ni=0;ni<8;ni++){
    ps[ni]  += __shfl_xor(ps[ni], 16, 64);  ps[ni]  += __shfl_xor(ps[ni], 32, 64);
    ps2[ni] += __shfl_xor(ps2[ni], 16, 64); ps2[ni] += __shfl_xor(ps2[ni], 32, 64);
  }
  if ((l>>4) == 0){
    #pragma unroll
    for (int ni=0;ni<8;ni++){
      atomicAdd(&lnS[ni*16+lr],  ps[ni]);
      atomicAdd(&lnS2[ni*16+lr], ps2[ni]);
    }
  }
  __syncthreads();
  if (t < 128){
    float mean = lnS[t]*(1.f/512.f);
    float var  = lnS2[t]*(1.f/512.f) - mean*mean;
    lnS[t] = mean; lnS2[t] = rsqrtf(var + 1e-5f);
  }
  __syncthreads();
  float* ob = out + (size_t)b*CDIM*NSEQ + n0;
  #pragma unroll
  for (int ni=0;ni<8;ni++){
    int col = ni*16 + lr;
    float mean = lnS[col], rstd = lnS2[col];
    #pragma unroll
    for (int mi=0;mi<4;mi++)
      #pragma unroll
      for (int r=0;r<4;r++){
        int row = w*64 + mi*16 + (l>>4)*4 + r;
        ob[(size_t)row*NSEQ + col] = (acc[mi][ni][r] - mean)*rstd*g[row];
      }
  }
}

extern "C" void kernel_launch(void* const* d_in, const int* in_sizes, int n_in,
                              void* d_out, int out_size, void* d_ws, size_t ws_size,
                              hipStream_t stream){
  const float* x     = (const float*)d_in[0];
  const float* w_qkv = (const float*)d_in[1];
  const float* w_out = (const float*)d_in[2];
  const float* b_out = (const float*)d_in[3];
  const float* g_out = (const float*)d_in[4];
  float* out = (float*)d_out;
  char* ws = (char*)d_ws;

  size_t off = 0;
  unsigned short* wq_bf = (unsigned short*)(ws + off); off += (size_t)O3*CDIM*2;          // 1.5 MB
  char* xT_region = ws + off;                          off += (size_t)NB*NSEQ*CDIM*2;     // 67 MB
  unsigned short* qkv_kv = (unsigned short*)(ws + off); off += (size_t)NB*1024*NSEQ*2;    // 134 MB
  unsigned short* qsmT   = (unsigned short*)(ws + off); off += (size_t)NB*NSEQ*CDIM*2;    // 67 MB
  if (off > ws_size) return;
  unsigned short* xT = (unsigned short*)xT_region;
  // aliases into xT region (xT dead after both GEMMs):
  float* kmaxp = (float*)(xT_region);
  float* ksump = (float*)(xT_region + (64<<10));
  float* ctx4  = (float*)(xT_region + (1<<20));
  unsigned short* weff = (unsigned short*)(xT_region + (16<<20));

  k_conv_w     <<<O3*CDIM/1024, 256, 0, stream>>>(w_qkv, wq_bf);
  k_transpose_x<<<dim3(NSEQ/64, CDIM/64, NB), 256, 0, stream>>>(x, xT);
  k_gemm_kv8   <<<dim3(NSEQ/256, 4, NB), 512, 0, stream>>>(wq_bf + (size_t)512*CDIM, xT, qkv_kv);
  k_gemm_q     <<<dim3(NSEQ/128, 4, NB), 256, 0, stream>>>(wq_bf, xT, qsmT);
  k_kstats     <<<NB*CDIM/4, 256, 0, stream>>>(qkv_kv, kmaxp, ksump);
  k_context    <<<dim3(NHEAD, NB, 4), 256, 0, stream>>>(qkv_kv, kmaxp, ksump, ctx4);
  k_weff       <<<dim3(NHEAD, NB, 4), 256, 0, stream>>>(ctx4, w_out, weff);
  k_out_ln     <<<dim3(NSEQ/128, NB), 512, 0, stream>>>(weff, qsmT, b_out, g_out, out);
}

// Round 5
// 379.934 us; speedup vs baseline: 1.0332x; 1.0332x over previous
//
#include <hip/hip_runtime.h>

#define NB 16
#define CDIM 512
#define NHEAD 8
#define DHEAD 64
#define NSEQ 4096
#define O3 1536

typedef __attribute__((ext_vector_type(8))) short short8;
typedef __attribute__((ext_vector_type(4))) float f32x4;
typedef __attribute__((ext_vector_type(4))) unsigned u32x4;
typedef __attribute__((ext_vector_type(2))) unsigned u32x2;
typedef __attribute__((ext_vector_type(4))) float fvec4;

__device__ __forceinline__ float bf2f(unsigned short u){
  union { unsigned u; float f; } v; v.u = ((unsigned)u) << 16; return v.f;
}
__device__ __forceinline__ unsigned short f2bf(float f){
  union { float f; unsigned u; } v; v.f = f;
  unsigned r = v.u + 0x7fffu + ((v.u >> 16) & 1u);
  return (unsigned short)(r >> 16);
}
__device__ __forceinline__ unsigned pack2(float a, float b){
  return (unsigned)f2bf(a) | ((unsigned)f2bf(b) << 16);
}
__device__ __forceinline__ void gld_lds16(const void* g, void* l){
  __builtin_amdgcn_global_load_lds(
      (const __attribute__((address_space(1))) unsigned*)g,
      (__attribute__((address_space(3))) unsigned*)l, 16, 0, 0);
}

// ---- w_qkv f32 -> bf16 ----
__global__ __launch_bounds__(256) void k_conv_w(const float* __restrict__ w,
                                                unsigned short* __restrict__ o){
  int i = (blockIdx.x*256 + threadIdx.x)*4;
  fvec4 v = *(const fvec4*)(w + i);
  u32x2 p; p[0] = pack2(v[0], v[1]); p[1] = pack2(v[2], v[3]);
  *(u32x2*)(o + i) = p;
}

// ---- x [b][c][n] f32 -> xT [b][n][c] bf16; 16B reads, 16B writes ----
__global__ __launch_bounds__(256) void k_transpose_x(const float* __restrict__ x,
                                                     unsigned short* __restrict__ xT){
  __shared__ unsigned short tile[64][65];
  int b = blockIdx.z, c0 = blockIdx.y*64, n0 = blockIdx.x*64;
  int t = threadIdx.x;
  const float* xb = x + ((size_t)b*CDIM + c0)*NSEQ + n0;
  #pragma unroll
  for (int i=0;i<4;i++){
    int idx = t + i*256;
    int r = idx>>4, c4 = (idx&15)*4;
    fvec4 v = *(const fvec4*)(xb + (size_t)r*NSEQ + c4);
    tile[r][c4]   = f2bf(v[0]);
    tile[r][c4+1] = f2bf(v[1]);
    tile[r][c4+2] = f2bf(v[2]);
    tile[r][c4+3] = f2bf(v[3]);
  }
  __syncthreads();
  unsigned short* ob = xT + ((size_t)b*NSEQ + n0)*CDIM + c0;
  #pragma unroll
  for (int i=0;i<2;i++){
    int chunk = t + i*256;                 // 512 chunks of 8 shorts
    int r = chunk>>3, c8 = (chunk&7)*8;    // r: n row, c8: channel col
    u32x4 p;
    #pragma unroll
    for (int k=0;k<4;k++)
      p[k] = (unsigned)tile[c8+2*k][r] | ((unsigned)tile[c8+2*k+1][r] << 16);
    *(u32x4*)(ob + (size_t)r*CDIM + c8) = p;
  }
}

// ---- k/v GEMM (lean r3 structure): C[b][o][n], o in [0,1024) ----
__global__ __launch_bounds__(256) void k_gemm_kv(const unsigned short* __restrict__ A,
                                                 const unsigned short* __restrict__ Bt,
                                                 unsigned short* __restrict__ KV){
  __shared__ unsigned short As[128*32];
  __shared__ unsigned short Bs[128*32];
  int b = blockIdx.z;
  int n0 = blockIdx.x*128, o0 = blockIdx.y*128;
  const unsigned short* Bb = Bt + (size_t)b*NSEQ*CDIM;
  unsigned short* Cb = KV + (size_t)b*1024*NSEQ;
  int t = threadIdx.x, w = t>>6, l = t&63;
  int lr = l&15, kq = (l>>4)*8;
  int wr = (w>>1)*64, wc = (w&1)*64;
  f32x4 acc[4][4];
  #pragma unroll
  for (int mi=0;mi<4;mi++)
    #pragma unroll
    for (int ni=0;ni<4;ni++) acc[mi][ni] = (f32x4){0.f,0.f,0.f,0.f};
  for (int k0=0;k0<CDIM;k0+=32){
    #pragma unroll
    for (int it=0;it<2;++it){
      int chunk = it*256 + t;
      int row = chunk>>2, kc = (chunk&3)*8;
      gld_lds16(A  + (size_t)(o0+row)*CDIM + k0 + kc, (char*)As + (size_t)chunk*16);
      gld_lds16(Bb + (size_t)(n0+row)*CDIM + k0 + kc, (char*)Bs + (size_t)chunk*16);
    }
    __syncthreads();
    short8 af[4], bfv[4];
    #pragma unroll
    for (int mi=0;mi<4;mi++) af[mi]  = *(const short8*)&As[(wr + mi*16 + lr)*32 + kq];
    #pragma unroll
    for (int ni=0;ni<4;ni++) bfv[ni] = *(const short8*)&Bs[(wc + ni*16 + lr)*32 + kq];
    #pragma unroll
    for (int mi=0;mi<4;mi++)
      #pragma unroll
      for (int ni=0;ni<4;ni++)
        acc[mi][ni] = __builtin_amdgcn_mfma_f32_16x16x32_bf16(af[mi], bfv[ni], acc[mi][ni], 0, 0, 0);
    __syncthreads();
  }
  #pragma unroll
  for (int mi=0;mi<4;mi++)
    #pragma unroll
    for (int ni=0;ni<4;ni++)
      #pragma unroll
      for (int r=0;r<4;r++){
        int row = o0 + wr + mi*16 + (l>>4)*4 + r;
        int col = n0 + wc + ni*16 + lr;
        Cb[(size_t)row*NSEQ + col] = f2bf(acc[mi][ni][r]);
      }
}

// ---- q GEMM + in-register head-softmax -> qsmT[b][n][c] bf16 ----
#define TS 136
__global__ __launch_bounds__(256) void k_gemm_q(const unsigned short* __restrict__ A,
                                                const unsigned short* __restrict__ Bt,
                                                unsigned short* __restrict__ qsmT){
  __shared__ unsigned short smem[64*TS];   // 17.4 KB; As/Bs alias first 16 KB
  unsigned short* As = smem;
  unsigned short* Bs = smem + 4096;
  int b = blockIdx.z;
  int n0 = blockIdx.x*128, o0 = blockIdx.y*128;
  const unsigned short* Bb = Bt + (size_t)b*NSEQ*CDIM;
  int t = threadIdx.x, w = t>>6, l = t&63;
  int lr = l&15, kq = (l>>4)*8;
  int wr = (w>>1)*64, wc = (w&1)*64;
  f32x4 acc[4][4];
  #pragma unroll
  for (int mi=0;mi<4;mi++)
    #pragma unroll
    for (int ni=0;ni<4;ni++) acc[mi][ni] = (f32x4){0.f,0.f,0.f,0.f};
  for (int k0=0;k0<CDIM;k0+=32){
    #pragma unroll
    for (int it=0;it<2;++it){
      int chunk = it*256 + t;
      int row = chunk>>2, kc = (chunk&3)*8;
      gld_lds16(A  + (size_t)(o0+row)*CDIM + k0 + kc, (char*)As + (size_t)chunk*16);
      gld_lds16(Bb + (size_t)(n0+row)*CDIM + k0 + kc, (char*)Bs + (size_t)chunk*16);
    }
    __syncthreads();
    short8 af[4], bfv[4];
    #pragma unroll
    for (int mi=0;mi<4;mi++) af[mi]  = *(const short8*)&As[(wr + mi*16 + lr)*32 + kq];
    #pragma unroll
    for (int ni=0;ni<4;ni++) bfv[ni] = *(const short8*)&Bs[(wc + ni*16 + lr)*32 + kq];
    #pragma unroll
    for (int mi=0;mi<4;mi++)
      #pragma unroll
      for (int ni=0;ni<4;ni++)
        acc[mi][ni] = __builtin_amdgcn_mfma_f32_16x16x32_bf16(af[mi], bfv[ni], acc[mi][ni], 0, 0, 0);
    __syncthreads();
  }
  unsigned pk[4][4][2];
  #pragma unroll
  for (int ni=0;ni<4;ni++){
    float mx = -1e30f;
    #pragma unroll
    for (int mi=0;mi<4;mi++)
      #pragma unroll
      for (int r=0;r<4;r++) mx = fmaxf(mx, acc[mi][ni][r]);
    mx = fmaxf(mx, __shfl_xor(mx, 16, 64));
    mx = fmaxf(mx, __shfl_xor(mx, 32, 64));
    float s = 0.f;
    #pragma unroll
    for (int mi=0;mi<4;mi++)
      #pragma unroll
      for (int r=0;r<4;r++){
        float p = __expf(acc[mi][ni][r] - mx);
        acc[mi][ni][r] = p; s += p;
      }
    s += __shfl_xor(s, 16, 64);
    s += __shfl_xor(s, 32, 64);
    float inv = 0.125f / s;
    #pragma unroll
    for (int mi=0;mi<4;mi++){
      pk[mi][ni][0] = pack2(acc[mi][ni][0]*inv, acc[mi][ni][1]*inv);
      pk[mi][ni][1] = pack2(acc[mi][ni][2]*inv, acc[mi][ni][3]*inv);
    }
  }
  #pragma unroll
  for (int ck=0;ck<2;++ck){
    if ((w&1) == ck){
      #pragma unroll
      for (int mi=0;mi<4;mi++)
        #pragma unroll
        for (int ni=0;ni<4;ni++){
          int idx = (ni*16 + lr)*TS + wr + mi*16 + (l>>4)*4;
          u32x2 p; p[0] = pk[mi][ni][0]; p[1] = pk[mi][ni][1];
          *(u32x2*)&smem[idx] = p;
        }
    }
    __syncthreads();
    int col = t>>2, rs = (t&3)*32;
    unsigned short* dst = qsmT + ((size_t)b*NSEQ + n0 + ck*64 + col)*CDIM + o0 + rs;
    #pragma unroll
    for (int j=0;j<4;++j)
      *(u32x4*)(dst + j*8) = *(const u32x4*)&smem[col*TS + rs + j*8];
    __syncthreads();
  }
}

// ---- partial context over n-chunk with CHUNK-LOCAL softmax (no kstats) ----
// writes unnormalized ctxp + per-row local max/sum; k_weff merges.
__global__ __launch_bounds__(256) void k_context(const unsigned short* __restrict__ KV,
                                                 float* __restrict__ ctx4,
                                                 float* __restrict__ maxp,
                                                 float* __restrict__ sump){
  __shared__ unsigned short Vs[64*64];
  int m = blockIdx.x, b = blockIdx.y, ch = blockIdx.z;
  int t = threadIdx.x, w = t>>6, l = t&63;
  int lr = l&15, kq = (l>>4)*8;
  const unsigned short* kbase = KV + ((size_t)b*1024 + m*64)*NSEQ;
  const unsigned short* vbase = KV + ((size_t)b*1024 + 512 + m*64)*NSEQ;
  int irow = w*16 + lr;
  int sub = l>>4;
  int nbeg = ch*1024;
  // ---- pass A: chunk-local row max (each lane scans 256 cols of irow) ----
  float mx = -1e30f;
  {
    const unsigned short* kp = kbase + (size_t)irow*NSEQ + nbeg + sub*256;
    #pragma unroll
    for (int it=0;it<32;++it){
      u32x4 kv4 = *(const u32x4*)(kp + it*8);
      #pragma unroll
      for (int c=0;c<4;++c){
        unsigned u = kv4[c];
        mx = fmaxf(mx, fmaxf(bf2f((unsigned short)u), bf2f((unsigned short)(u>>16))));
      }
    }
    mx = fmaxf(mx, __shfl_xor(mx, 16, 64));
    mx = fmaxf(mx, __shfl_xor(mx, 32, 64));
  }
  // ---- pass B: exp(k - mx) MFMA with v, accumulate row sums ----
  float rsum = 0.f;
  f32x4 acc[4];
  #pragma unroll
  for (int jf=0;jf<4;++jf) acc[jf] = (f32x4){0.f,0.f,0.f,0.f};
  for (int n0=nbeg;n0<nbeg+1024;n0+=64){
    #pragma unroll
    for (int it=0;it<2;++it){
      int chunk = it*256 + t;
      int row = chunk>>3, kc = (chunk&7)*8;
      gld_lds16(vbase + (size_t)row*NSEQ + n0 + kc, (char*)Vs + (size_t)chunk*16);
    }
    __syncthreads();
    #pragma unroll
    for (int kk=0;kk<2;++kk){
      u32x4 kraw = *(const u32x4*)(kbase + (size_t)irow*NSEQ + n0 + kk*32 + kq);
      short8 af;
      #pragma unroll
      for (int c=0;c<4;++c){
        unsigned u = kraw[c];
        float f0 = __expf(bf2f((unsigned short)u) - mx);
        float f1 = __expf(bf2f((unsigned short)(u>>16)) - mx);
        rsum += f0 + f1;
        af[c*2]   = (short)f2bf(f0);
        af[c*2+1] = (short)f2bf(f1);
      }
      #pragma unroll
      for (int jf=0;jf<4;++jf){
        short8 bv = *(const short8*)&Vs[(jf*16+lr)*64 + kk*32 + kq];
        acc[jf] = __builtin_amdgcn_mfma_f32_16x16x32_bf16(af, bv, acc[jf], 0, 0, 0);
      }
    }
    __syncthreads();
  }
  rsum += __shfl_xor(rsum, 16, 64);
  rsum += __shfl_xor(rsum, 32, 64);
  size_t sbase = (((size_t)ch*NB + b)*NHEAD + m)*64;
  if (sub == 0){ maxp[sbase + irow] = mx; sump[sbase + irow] = rsum; }
  float* cb = ctx4 + (((size_t)ch*NB + b)*NHEAD + m)*4096;
  #pragma unroll
  for (int jf=0;jf<4;++jf)
    #pragma unroll
    for (int r=0;r<4;++r){
      int i = w*16 + (l>>4)*4 + r;
      int j = jf*16 + lr;
      cb[i*64 + j] = acc[jf][r];
    }
}

// ---- W_eff: merge 4 chunk-partials (flash-style) then fold w_out ----
__global__ __launch_bounds__(256) void k_weff(const float* __restrict__ ctx4,
                                              const float* __restrict__ maxp,
                                              const float* __restrict__ sump,
                                              const float* __restrict__ wout,
                                              unsigned short* __restrict__ weff){
  __shared__ float cs[64][65];
  __shared__ float wch[4][64];
  __shared__ float invZ[64];
  int m = blockIdx.x, b = blockIdx.y, z = blockIdx.z;
  int t = threadIdx.x, w = t>>6, l = t&63;
  const size_t chs = (size_t)NB*NHEAD*4096;
  const size_t sts = (size_t)NB*NHEAD*64;
  size_t sb = ((size_t)b*NHEAD + m)*64;
  if (t < 64){
    float m0 = maxp[sb + t], m1 = maxp[sb + sts + t];
    float m2 = maxp[sb + 2*sts + t], m3 = maxp[sb + 3*sts + t];
    float M = fmaxf(fmaxf(m0,m1), fmaxf(m2,m3));
    float w0 = __expf(m0-M), w1 = __expf(m1-M), w2 = __expf(m2-M), w3 = __expf(m3-M);
    float Z = sump[sb + t]*w0 + sump[sb + sts + t]*w1
            + sump[sb + 2*sts + t]*w2 + sump[sb + 3*sts + t]*w3;
    wch[0][t] = w0; wch[1][t] = w1; wch[2][t] = w2; wch[3][t] = w3;
    invZ[t] = 1.f/Z;
  }
  __syncthreads();
  const float* cb = ctx4 + ((size_t)b*NHEAD + m)*4096;
  for (int idx=t; idx<4096; idx+=256){
    int i = idx>>6;
    cs[i][idx&63] = (cb[idx]*wch[0][i] + cb[idx+chs]*wch[1][i]
                   + cb[idx+2*chs]*wch[2][i] + cb[idx+3*chs]*wch[3][i]) * invZ[i];
  }
  __syncthreads();
  for (int oo=0;oo<32;++oo){
    int o = z*128 + w*32 + oo;
    float acc = 0.f;
    #pragma unroll
    for (int j=0;j<64;++j) acc += wout[(size_t)o*CDIM + m*64 + j] * cs[l][j];
    weff[((size_t)b*CDIM + o)*CDIM + m*64 + l] = f2bf(acc);
  }
}

// ---- fused final GEMM + bias + channel-LN: 512(o) x 128(n) per block ----
__global__ __launch_bounds__(512) void k_out_ln(const unsigned short* __restrict__ Weff,
                                                const unsigned short* __restrict__ QT,
                                                const float* __restrict__ bias,
                                                const float* __restrict__ g,
                                                float* __restrict__ out){
  __shared__ unsigned short As[512*32];   // 32 KB
  __shared__ unsigned short Bs[128*32];   //  8 KB
  __shared__ float lnS[128], lnS2[128];
  int b = blockIdx.y, n0 = blockIdx.x*128;
  const unsigned short* Ab = Weff + (size_t)b*CDIM*CDIM;
  const unsigned short* Bb = QT + ((size_t)b*NSEQ + n0)*CDIM;
  int t = threadIdx.x, w = t>>6, l = t&63;
  int lr = l&15, kq = (l>>4)*8;
  f32x4 acc[4][8];
  #pragma unroll
  for (int mi=0;mi<4;mi++)
    #pragma unroll
    for (int ni=0;ni<8;ni++) acc[mi][ni] = (f32x4){0.f,0.f,0.f,0.f};
  for (int k0=0;k0<CDIM;k0+=32){
    #pragma unroll
    for (int it=0;it<4;++it){
      int chunk = it*512 + t;
      int row = chunk>>2, kc = (chunk&3)*8;
      gld_lds16(Ab + (size_t)row*CDIM + k0 + kc, (char*)As + (size_t)chunk*16);
    }
    {
      int row = t>>2, kc = (t&3)*8;
      gld_lds16(Bb + (size_t)row*CDIM + k0 + kc, (char*)Bs + (size_t)t*16);
    }
    __syncthreads();
    short8 af[4], bfv[8];
    #pragma unroll
    for (int mi=0;mi<4;mi++) af[mi]  = *(const short8*)&As[(w*64 + mi*16 + lr)*32 + kq];
    #pragma unroll
    for (int ni=0;ni<8;ni++) bfv[ni] = *(const short8*)&Bs[(ni*16 + lr)*32 + kq];
    #pragma unroll
    for (int mi=0;mi<4;mi++)
      #pragma unroll
      for (int ni=0;ni<8;ni++)
        acc[mi][ni] = __builtin_amdgcn_mfma_f32_16x16x32_bf16(af[mi], bfv[ni], acc[mi][ni], 0, 0, 0);
    __syncthreads();
  }
  if (t < 128){ lnS[t] = 0.f; lnS2[t] = 0.f; }
  __syncthreads();
  float ps[8], ps2[8];
  #pragma unroll
  for (int ni=0;ni<8;ni++){ ps[ni]=0.f; ps2[ni]=0.f; }
  #pragma unroll
  for (int mi=0;mi<4;mi++)
    #pragma unroll
    for (int r=0;r<4;r++){
      int row = w*64 + mi*16 + (l>>4)*4 + r;
      float bb = bias[row];
      #pragma unroll
      for (int ni=0;ni<8;ni++){
        float v = acc[mi][ni][r] + bb;
        acc[mi][ni][r] = v;
        ps[ni] += v; ps2[ni] += v*v;
      }
    }
  #pragma unroll
  for (int ni=0;ni<8;ni++){
    ps[ni]  += __shfl_xor(ps[ni], 16, 64);  ps[ni]  += __shfl_xor(ps[ni], 32, 64);
    ps2[ni] += __shfl_xor(ps2[ni], 16, 64); ps2[ni] += __shfl_xor(ps2[ni], 32, 64);
  }
  if ((l>>4) == 0){
    #pragma unroll
    for (int ni=0;ni<8;ni++){
      atomicAdd(&lnS[ni*16+lr],  ps[ni]);
      atomicAdd(&lnS2[ni*16+lr], ps2[ni]);
    }
  }
  __syncthreads();
  if (t < 128){
    float mean = lnS[t]*(1.f/512.f);
    float var  = lnS2[t]*(1.f/512.f) - mean*mean;
    lnS[t] = mean; lnS2[t] = rsqrtf(var + 1e-5f);
  }
  __syncthreads();
  float* ob = out + (size_t)b*CDIM*NSEQ + n0;
  #pragma unroll
  for (int ni=0;ni<8;ni++){
    int col = ni*16 + lr;
    float mean = lnS[col], rstd = lnS2[col];
    #pragma unroll
    for (int mi=0;mi<4;mi++)
      #pragma unroll
      for (int r=0;r<4;r++){
        int row = w*64 + mi*16 + (l>>4)*4 + r;
        ob[(size_t)row*NSEQ + col] = (acc[mi][ni][r] - mean)*rstd*g[row];
      }
  }
}

extern "C" void kernel_launch(void* const* d_in, const int* in_sizes, int n_in,
                              void* d_out, int out_size, void* d_ws, size_t ws_size,
                              hipStream_t stream){
  const float* x     = (const float*)d_in[0];
  const float* w_qkv = (const float*)d_in[1];
  const float* w_out = (const float*)d_in[2];
  const float* b_out = (const float*)d_in[3];
  const float* g_out = (const float*)d_in[4];
  float* out = (float*)d_out;
  char* ws = (char*)d_ws;

  size_t off = 0;
  unsigned short* wq_bf = (unsigned short*)(ws + off); off += (size_t)O3*CDIM*2;          // 1.5 MB
  char* xT_region = ws + off;                          off += (size_t)NB*NSEQ*CDIM*2;     // 67 MB
  unsigned short* qkv_kv = (unsigned short*)(ws + off); off += (size_t)NB*1024*NSEQ*2;    // 134 MB
  unsigned short* qsmT   = (unsigned short*)(ws + off); off += (size_t)NB*NSEQ*CDIM*2;    // 67 MB
  if (off > ws_size) return;
  unsigned short* xT = (unsigned short*)xT_region;
  // aliases into xT region (xT dead after both GEMMs):
  float* maxp = (float*)(xT_region);                        // 128 KB (4 chunks x 16 x 8 x 64)
  float* sump = (float*)(xT_region + (256<<10));            // 128 KB
  float* ctx4 = (float*)(xT_region + (1<<20));              // 8 MB (4 chunks)
  unsigned short* weff = (unsigned short*)(xT_region + (16<<20)); // 8.4 MB

  k_conv_w     <<<O3*CDIM/1024, 256, 0, stream>>>(w_qkv, wq_bf);
  k_transpose_x<<<dim3(NSEQ/64, CDIM/64, NB), 256, 0, stream>>>(x, xT);
  k_gemm_kv    <<<dim3(NSEQ/128, 8, NB), 256, 0, stream>>>(wq_bf + (size_t)512*CDIM, xT, qkv_kv);
  k_gemm_q     <<<dim3(NSEQ/128, 4, NB), 256, 0, stream>>>(wq_bf, xT, qsmT);
  k_context    <<<dim3(NHEAD, NB, 4), 256, 0, stream>>>(qkv_kv, ctx4, maxp, sump);
  k_weff       <<<dim3(NHEAD, NB, 4), 256, 0, stream>>>(ctx4, maxp, sump, w_out, weff);
  k_out_ln     <<<dim3(NSEQ/128, NB), 512, 0, stream>>>(weff, qsmT, b_out, g_out, out);
}

// Round 6
// 373.397 us; speedup vs baseline: 1.0513x; 1.0175x over previous
//
#include <hip/hip_runtime.h>

#define NB 16
#define CDIM 512
#define NHEAD 8
#define DHEAD 64
#define NSEQ 4096
#define O3 1536

typedef __attribute__((ext_vector_type(8))) short short8;
typedef __attribute__((ext_vector_type(4))) float f32x4;
typedef __attribute__((ext_vector_type(4))) unsigned u32x4;
typedef __attribute__((ext_vector_type(2))) unsigned u32x2;
typedef __attribute__((ext_vector_type(4))) float fvec4;

__device__ __forceinline__ float bf2f(unsigned short u){
  union { unsigned u; float f; } v; v.u = ((unsigned)u) << 16; return v.f;
}
__device__ __forceinline__ unsigned short f2bf(float f){
  union { float f; unsigned u; } v; v.f = f;
  unsigned r = v.u + 0x7fffu + ((v.u >> 16) & 1u);
  return (unsigned short)(r >> 16);
}
__device__ __forceinline__ unsigned pack2(float a, float b){
  return (unsigned)f2bf(a) | ((unsigned)f2bf(b) << 16);
}
__device__ __forceinline__ void gld_lds16(const void* g, void* l){
  __builtin_amdgcn_global_load_lds(
      (const __attribute__((address_space(1))) unsigned*)g,
      (__attribute__((address_space(3))) unsigned*)l, 16, 0, 0);
}

// ---- w_qkv f32 -> bf16 ----
__global__ __launch_bounds__(256) void k_conv_w(const float* __restrict__ w,
                                                unsigned short* __restrict__ o){
  int i = (blockIdx.x*256 + threadIdx.x)*4;
  fvec4 v = *(const fvec4*)(w + i);
  u32x2 p; p[0] = pack2(v[0], v[1]); p[1] = pack2(v[2], v[3]);
  *(u32x2*)(o + i) = p;
}

// ---- x [b][c][n] f32 -> xT [b][n][c] bf16; 16B reads, 16B writes ----
__global__ __launch_bounds__(256) void k_transpose_x(const float* __restrict__ x,
                                                     unsigned short* __restrict__ xT){
  __shared__ unsigned short tile[64][65];
  int b = blockIdx.z, c0 = blockIdx.y*64, n0 = blockIdx.x*64;
  int t = threadIdx.x;
  const float* xb = x + ((size_t)b*CDIM + c0)*NSEQ + n0;
  #pragma unroll
  for (int i=0;i<4;i++){
    int idx = t + i*256;
    int r = idx>>4, c4 = (idx&15)*4;
    fvec4 v = *(const fvec4*)(xb + (size_t)r*NSEQ + c4);
    tile[r][c4]   = f2bf(v[0]);
    tile[r][c4+1] = f2bf(v[1]);
    tile[r][c4+2] = f2bf(v[2]);
    tile[r][c4+3] = f2bf(v[3]);
  }
  __syncthreads();
  unsigned short* ob = xT + ((size_t)b*NSEQ + n0)*CDIM + c0;
  #pragma unroll
  for (int i=0;i<2;i++){
    int chunk = t + i*256;                 // 512 chunks of 8 shorts
    int r = chunk>>3, c8 = (chunk&7)*8;    // r: n row, c8: channel col
    u32x4 p;
    #pragma unroll
    for (int k=0;k<4;k++)
      p[k] = (unsigned)tile[c8+2*k][r] | ((unsigned)tile[c8+2*k+1][r] << 16);
    *(u32x4*)(ob + (size_t)r*CDIM + c8) = p;
  }
}

// ---- k/v GEMM: BK=64 via two split 128x32 half-tiles (half the barriers,
//      identical per-half addressing/conflict pattern to the proven BK=32) ----
__global__ __launch_bounds__(256) void k_gemm_kv(const unsigned short* __restrict__ A,
                                                 const unsigned short* __restrict__ Bt,
                                                 unsigned short* __restrict__ KV){
  __shared__ unsigned short As[2][128*32];   // 16 KB
  __shared__ unsigned short Bs[2][128*32];   // 16 KB
  int b = blockIdx.z;
  int n0 = blockIdx.x*128, o0 = blockIdx.y*128;
  const unsigned short* Bb = Bt + (size_t)b*NSEQ*CDIM;
  unsigned short* Cb = KV + (size_t)b*1024*NSEQ;
  int t = threadIdx.x, w = t>>6, l = t&63;
  int lr = l&15, kq = (l>>4)*8;
  int wr = (w>>1)*64, wc = (w&1)*64;
  f32x4 acc[4][4];
  #pragma unroll
  for (int mi=0;mi<4;mi++)
    #pragma unroll
    for (int ni=0;ni<4;ni++) acc[mi][ni] = (f32x4){0.f,0.f,0.f,0.f};
  for (int k0=0;k0<CDIM;k0+=64){
    #pragma unroll
    for (int h=0;h<2;++h){
      #pragma unroll
      for (int it=0;it<2;++it){
        int chunk = it*256 + t;
        int row = chunk>>2, kc = (chunk&3)*8;
        gld_lds16(A  + (size_t)(o0+row)*CDIM + k0 + h*32 + kc, (char*)As[h] + (size_t)chunk*16);
        gld_lds16(Bb + (size_t)(n0+row)*CDIM + k0 + h*32 + kc, (char*)Bs[h] + (size_t)chunk*16);
      }
    }
    __syncthreads();
    #pragma unroll
    for (int h=0;h<2;++h){
      short8 af[4], bfv[4];
      #pragma unroll
      for (int mi=0;mi<4;mi++) af[mi]  = *(const short8*)&As[h][(wr + mi*16 + lr)*32 + kq];
      #pragma unroll
      for (int ni=0;ni<4;ni++) bfv[ni] = *(const short8*)&Bs[h][(wc + ni*16 + lr)*32 + kq];
      #pragma unroll
      for (int mi=0;mi<4;mi++)
        #pragma unroll
        for (int ni=0;ni<4;ni++)
          acc[mi][ni] = __builtin_amdgcn_mfma_f32_16x16x32_bf16(af[mi], bfv[ni], acc[mi][ni], 0, 0, 0);
    }
    __syncthreads();
  }
  #pragma unroll
  for (int mi=0;mi<4;mi++)
    #pragma unroll
    for (int ni=0;ni<4;ni++)
      #pragma unroll
      for (int r=0;r<4;r++){
        int row = o0 + wr + mi*16 + (l>>4)*4 + r;
        int col = n0 + wc + ni*16 + lr;
        Cb[(size_t)row*NSEQ + col] = f2bf(acc[mi][ni][r]);
      }
}

// ---- q GEMM (BK=64 split halves) + in-register head-softmax -> qsmT ----
#define TS 136
__global__ __launch_bounds__(256) void k_gemm_q(const unsigned short* __restrict__ A,
                                                const unsigned short* __restrict__ Bt,
                                                unsigned short* __restrict__ qsmT){
  __shared__ unsigned short smem[128*128];   // 32 KB: 4x 128x32 halves; epilogue tile aliases
  int b = blockIdx.z;
  int n0 = blockIdx.x*128, o0 = blockIdx.y*128;
  const unsigned short* Bb = Bt + (size_t)b*NSEQ*CDIM;
  int t = threadIdx.x, w = t>>6, l = t&63;
  int lr = l&15, kq = (l>>4)*8;
  int wr = (w>>1)*64, wc = (w&1)*64;
  f32x4 acc[4][4];
  #pragma unroll
  for (int mi=0;mi<4;mi++)
    #pragma unroll
    for (int ni=0;ni<4;ni++) acc[mi][ni] = (f32x4){0.f,0.f,0.f,0.f};
  for (int k0=0;k0<CDIM;k0+=64){
    #pragma unroll
    for (int h=0;h<2;++h){
      unsigned short* Ash = smem + h*4096;
      unsigned short* Bsh = smem + 8192 + h*4096;
      #pragma unroll
      for (int it=0;it<2;++it){
        int chunk = it*256 + t;
        int row = chunk>>2, kc = (chunk&3)*8;
        gld_lds16(A  + (size_t)(o0+row)*CDIM + k0 + h*32 + kc, (char*)Ash + (size_t)chunk*16);
        gld_lds16(Bb + (size_t)(n0+row)*CDIM + k0 + h*32 + kc, (char*)Bsh + (size_t)chunk*16);
      }
    }
    __syncthreads();
    #pragma unroll
    for (int h=0;h<2;++h){
      const unsigned short* Ash = smem + h*4096;
      const unsigned short* Bsh = smem + 8192 + h*4096;
      short8 af[4], bfv[4];
      #pragma unroll
      for (int mi=0;mi<4;mi++) af[mi]  = *(const short8*)&Ash[(wr + mi*16 + lr)*32 + kq];
      #pragma unroll
      for (int ni=0;ni<4;ni++) bfv[ni] = *(const short8*)&Bsh[(wc + ni*16 + lr)*32 + kq];
      #pragma unroll
      for (int mi=0;mi<4;mi++)
        #pragma unroll
        for (int ni=0;ni<4;ni++)
          acc[mi][ni] = __builtin_amdgcn_mfma_f32_16x16x32_bf16(af[mi], bfv[ni], acc[mi][ni], 0, 0, 0);
    }
    __syncthreads();
  }
  // in-register softmax over d (wave's 64 rows = one head) per column
  unsigned pk[4][4][2];
  #pragma unroll
  for (int ni=0;ni<4;ni++){
    float mx = -1e30f;
    #pragma unroll
    for (int mi=0;mi<4;mi++)
      #pragma unroll
      for (int r=0;r<4;r++) mx = fmaxf(mx, acc[mi][ni][r]);
    mx = fmaxf(mx, __shfl_xor(mx, 16, 64));
    mx = fmaxf(mx, __shfl_xor(mx, 32, 64));
    float s = 0.f;
    #pragma unroll
    for (int mi=0;mi<4;mi++)
      #pragma unroll
      for (int r=0;r<4;r++){
        float p = __expf(acc[mi][ni][r] - mx);
        acc[mi][ni][r] = p; s += p;
      }
    s += __shfl_xor(s, 16, 64);
    s += __shfl_xor(s, 32, 64);
    float inv = 0.125f / s;
    #pragma unroll
    for (int mi=0;mi<4;mi++){
      pk[mi][ni][0] = pack2(acc[mi][ni][0]*inv, acc[mi][ni][1]*inv);
      pk[mi][ni][1] = pack2(acc[mi][ni][2]*inv, acc[mi][ni][3]*inv);
    }
  }
  #pragma unroll
  for (int ck=0;ck<2;++ck){
    if ((w&1) == ck){
      #pragma unroll
      for (int mi=0;mi<4;mi++)
        #pragma unroll
        for (int ni=0;ni<4;ni++){
          int idx = (ni*16 + lr)*TS + wr + mi*16 + (l>>4)*4;
          u32x2 p; p[0] = pk[mi][ni][0]; p[1] = pk[mi][ni][1];
          *(u32x2*)&smem[idx] = p;
        }
    }
    __syncthreads();
    int col = t>>2, rs = (t&3)*32;
    unsigned short* dst = qsmT + ((size_t)b*NSEQ + n0 + ck*64 + col)*CDIM + o0 + rs;
    #pragma unroll
    for (int j=0;j<4;++j)
      *(u32x4*)(dst + j*8) = *(const u32x4*)&smem[col*TS + rs + j*8];
    __syncthreads();
  }
}

// ---- partial context over n-chunk, NO max pass: exp(k) directly ----
// writes unnormalized ctxp + per-row exp-sum; k_weff merges (plain sums).
__global__ __launch_bounds__(256) void k_context(const unsigned short* __restrict__ KV,
                                                 float* __restrict__ ctx4,
                                                 float* __restrict__ sump){
  __shared__ unsigned short Vs[64*64];
  int m = blockIdx.x, b = blockIdx.y, ch = blockIdx.z;
  int t = threadIdx.x, w = t>>6, l = t&63;
  int lr = l&15, kq = (l>>4)*8;
  const unsigned short* kbase = KV + ((size_t)b*1024 + m*64)*NSEQ;
  const unsigned short* vbase = KV + ((size_t)b*1024 + 512 + m*64)*NSEQ;
  int irow = w*16 + lr;
  int sub = l>>4;
  int nbeg = ch*1024;
  float rsum = 0.f;
  f32x4 acc[4];
  #pragma unroll
  for (int jf=0;jf<4;++jf) acc[jf] = (f32x4){0.f,0.f,0.f,0.f};
  for (int n0=nbeg;n0<nbeg+1024;n0+=64){
    #pragma unroll
    for (int it=0;it<2;++it){
      int chunk = it*256 + t;
      int row = chunk>>3, kc = (chunk&7)*8;
      gld_lds16(vbase + (size_t)row*NSEQ + n0 + kc, (char*)Vs + (size_t)chunk*16);
    }
    __syncthreads();
    #pragma unroll
    for (int kk=0;kk<2;++kk){
      u32x4 kraw = *(const u32x4*)(kbase + (size_t)irow*NSEQ + n0 + kk*32 + kq);
      short8 af;
      #pragma unroll
      for (int c=0;c<4;++c){
        unsigned u = kraw[c];
        float f0 = __expf(bf2f((unsigned short)u));
        float f1 = __expf(bf2f((unsigned short)(u>>16)));
        rsum += f0 + f1;
        af[c*2]   = (short)f2bf(f0);
        af[c*2+1] = (short)f2bf(f1);
      }
      #pragma unroll
      for (int jf=0;jf<4;++jf){
        short8 bv = *(const short8*)&Vs[(jf*16+lr)*64 + kk*32 + kq];
        acc[jf] = __builtin_amdgcn_mfma_f32_16x16x32_bf16(af, bv, acc[jf], 0, 0, 0);
      }
    }
    __syncthreads();
  }
  rsum += __shfl_xor(rsum, 16, 64);
  rsum += __shfl_xor(rsum, 32, 64);
  size_t sbase = (((size_t)ch*NB + b)*NHEAD + m)*64;
  if (sub == 0) sump[sbase + irow] = rsum;
  float* cb = ctx4 + (((size_t)ch*NB + b)*NHEAD + m)*4096;
  #pragma unroll
  for (int jf=0;jf<4;++jf)
    #pragma unroll
    for (int r=0;r<4;++r){
      int i = w*16 + (l>>4)*4 + r;
      int j = jf*16 + lr;
      cb[i*64 + j] = acc[jf][r];
    }
}

// ---- W_eff: plain-sum merge of 4 chunk-partials, then fold w_out ----
__global__ __launch_bounds__(256) void k_weff(const float* __restrict__ ctx4,
                                              const float* __restrict__ sump,
                                              const float* __restrict__ wout,
                                              unsigned short* __restrict__ weff){
  __shared__ float cs[64][65];
  __shared__ float invZ[64];
  int m = blockIdx.x, b = blockIdx.y, z = blockIdx.z;
  int t = threadIdx.x, w = t>>6, l = t&63;
  const size_t chs = (size_t)NB*NHEAD*4096;
  const size_t sts = (size_t)NB*NHEAD*64;
  size_t sb = ((size_t)b*NHEAD + m)*64;
  if (t < 64){
    float Z = sump[sb + t] + sump[sb + sts + t]
            + sump[sb + 2*sts + t] + sump[sb + 3*sts + t];
    invZ[t] = 1.f/Z;
  }
  __syncthreads();
  const float* cb = ctx4 + ((size_t)b*NHEAD + m)*4096;
  for (int idx=t; idx<4096; idx+=256){
    int i = idx>>6;
    cs[i][idx&63] = (cb[idx] + cb[idx+chs] + cb[idx+2*chs] + cb[idx+3*chs]) * invZ[i];
  }
  __syncthreads();
  for (int oo=0;oo<32;++oo){
    int o = z*128 + w*32 + oo;
    float acc = 0.f;
    #pragma unroll
    for (int j=0;j<64;++j) acc += wout[(size_t)o*CDIM + m*64 + j] * cs[l][j];
    weff[((size_t)b*CDIM + o)*CDIM + m*64 + l] = f2bf(acc);
  }
}

// ---- fused final GEMM + bias + channel-LN: 512(o) x 128(n) per block ----
__global__ __launch_bounds__(512) void k_out_ln(const unsigned short* __restrict__ Weff,
                                                const unsigned short* __restrict__ QT,
                                                const float* __restrict__ bias,
                                                const float* __restrict__ g,
                                                float* __restrict__ out){
  __shared__ unsigned short As[512*32];   // 32 KB
  __shared__ unsigned short Bs[128*32];   //  8 KB
  __shared__ float lnS[128], lnS2[128];
  int b = blockIdx.y, n0 = blockIdx.x*128;
  const unsigned short* Ab = Weff + (size_t)b*CDIM*CDIM;
  const unsigned short* Bb = QT + ((size_t)b*NSEQ + n0)*CDIM;
  int t = threadIdx.x, w = t>>6, l = t&63;
  int lr = l&15, kq = (l>>4)*8;
  f32x4 acc[4][8];
  #pragma unroll
  for (int mi=0;mi<4;mi++)
    #pragma unroll
    for (int ni=0;ni<8;ni++) acc[mi][ni] = (f32x4){0.f,0.f,0.f,0.f};
  for (int k0=0;k0<CDIM;k0+=32){
    #pragma unroll
    for (int it=0;it<4;++it){
      int chunk = it*512 + t;
      int row = chunk>>2, kc = (chunk&3)*8;
      gld_lds16(Ab + (size_t)row*CDIM + k0 + kc, (char*)As + (size_t)chunk*16);
    }
    {
      int row = t>>2, kc = (t&3)*8;
      gld_lds16(Bb + (size_t)row*CDIM + k0 + kc, (char*)Bs + (size_t)t*16);
    }
    __syncthreads();
    short8 af[4], bfv[8];
    #pragma unroll
    for (int mi=0;mi<4;mi++) af[mi]  = *(const short8*)&As[(w*64 + mi*16 + lr)*32 + kq];
    #pragma unroll
    for (int ni=0;ni<8;ni++) bfv[ni] = *(const short8*)&Bs[(ni*16 + lr)*32 + kq];
    #pragma unroll
    for (int mi=0;mi<4;mi++)
      #pragma unroll
      for (int ni=0;ni<8;ni++)
        acc[mi][ni] = __builtin_amdgcn_mfma_f32_16x16x32_bf16(af[mi], bfv[ni], acc[mi][ni], 0, 0, 0);
    __syncthreads();
  }
  if (t < 128){ lnS[t] = 0.f; lnS2[t] = 0.f; }
  __syncthreads();
  float ps[8], ps2[8];
  #pragma unroll
  for (int ni=0;ni<8;ni++){ ps[ni]=0.f; ps2[ni]=0.f; }
  #pragma unroll
  for (int mi=0;mi<4;mi++)
    #pragma unroll
    for (int r=0;r<4;r++){
      int row = w*64 + mi*16 + (l>>4)*4 + r;
      float bb = bias[row];
      #pragma unroll
      for (int ni=0;ni<8;ni++){
        float v = acc[mi][ni][r] + bb;
        acc[mi][ni][r] = v;
        ps[ni] += v; ps2[ni] += v*v;
      }
    }
  #pragma unroll
  for (int ni=0;ni<8;ni++){
    ps[ni]  += __shfl_xor(ps[ni], 16, 64);  ps[ni]  += __shfl_xor(ps[ni], 32, 64);
    ps2[ni] += __shfl_xor(ps2[ni], 16, 64); ps2[ni] += __shfl_xor(ps2[ni], 32, 64);
  }
  if ((l>>4) == 0){
    #pragma unroll
    for (int ni=0;ni<8;ni++){
      atomicAdd(&lnS[ni*16+lr],  ps[ni]);
      atomicAdd(&lnS2[ni*16+lr], ps2[ni]);
    }
  }
  __syncthreads();
  if (t < 128){
    float mean = lnS[t]*(1.f/512.f);
    float var  = lnS2[t]*(1.f/512.f) - mean*mean;
    lnS[t] = mean; lnS2[t] = rsqrtf(var + 1e-5f);
  }
  __syncthreads();
  float* ob = out + (size_t)b*CDIM*NSEQ + n0;
  #pragma unroll
  for (int ni=0;ni<8;ni++){
    int col = ni*16 + lr;
    float mean = lnS[col], rstd = lnS2[col];
    #pragma unroll
    for (int mi=0;mi<4;mi++)
      #pragma unroll
      for (int r=0;r<4;r++){
        int row = w*64 + mi*16 + (l>>4)*4 + r;
        ob[(size_t)row*NSEQ + col] = (acc[mi][ni][r] - mean)*rstd*g[row];
      }
  }
}

extern "C" void kernel_launch(void* const* d_in, const int* in_sizes, int n_in,
                              void* d_out, int out_size, void* d_ws, size_t ws_size,
                              hipStream_t stream){
  const float* x     = (const float*)d_in[0];
  const float* w_qkv = (const float*)d_in[1];
  const float* w_out = (const float*)d_in[2];
  const float* b_out = (const float*)d_in[3];
  const float* g_out = (const float*)d_in[4];
  float* out = (float*)d_out;
  char* ws = (char*)d_ws;

  size_t off = 0;
  unsigned short* wq_bf = (unsigned short*)(ws + off); off += (size_t)O3*CDIM*2;          // 1.5 MB
  char* xT_region = ws + off;                          off += (size_t)NB*NSEQ*CDIM*2;     // 67 MB
  unsigned short* qkv_kv = (unsigned short*)(ws + off); off += (size_t)NB*1024*NSEQ*2;    // 134 MB
  unsigned short* qsmT   = (unsigned short*)(ws + off); off += (size_t)NB*NSEQ*CDIM*2;    // 67 MB
  if (off > ws_size) return;
  unsigned short* xT = (unsigned short*)xT_region;
  // aliases into xT region (xT dead after both GEMMs):
  float* sump = (float*)(xT_region);                        // 128 KB (4 chunks x 16 x 8 x 64)
  float* ctx4 = (float*)(xT_region + (1<<20));              // 8 MB (4 chunks)
  unsigned short* weff = (unsigned short*)(xT_region + (16<<20)); // 8.4 MB

  k_conv_w     <<<O3*CDIM/1024, 256, 0, stream>>>(w_qkv, wq_bf);
  k_transpose_x<<<dim3(NSEQ/64, CDIM/64, NB), 256, 0, stream>>>(x, xT);
  k_gemm_kv    <<<dim3(NSEQ/128, 8, NB), 256, 0, stream>>>(wq_bf + (size_t)512*CDIM, xT, qkv_kv);
  k_gemm_q     <<<dim3(NSEQ/128, 4, NB), 256, 0, stream>>>(wq_bf, xT, qsmT);
  k_context    <<<dim3(NHEAD, NB, 4), 256, 0, stream>>>(qkv_kv, ctx4, sump);
  k_weff       <<<dim3(NHEAD, NB, 4), 256, 0, stream>>>(ctx4, sump, w_out, weff);
  k_out_ln     <<<dim3(NSEQ/128, NB), 512, 0, stream>>>(weff, qsmT, b_out, g_out, out);
}